// Round 15
// baseline (145.374 us; speedup 1.0000x reference)
//
#include <hip/hip_runtime.h>
#include <cstdint>
#include <type_traits>

// GPT MHA forward. B=2, T=2048, C=1024, H=16, d=64.
// cast x->bf16 | transpose weights (wq pre-scaled 0.125*log2e) | bias concat
// | QKV GEMM (128x128, BK=32, gload_lds, 2-PHASE dbuf, 2D-XCD L2 tiling)
// | V-transpose | causal flash attn (R12 body + BALANCED zigzag qt decode)
// | out-proj GEMM (same 2-phase structure).

#define TSEQ  2048
#define BATCH 2
#define CDIM  1024
#define NHEAD 16
#define DHEAD 64
#define NROWS (BATCH * TSEQ)  // 4096

// 0.125 (1/sqrt(d)) * log2(e): folded into wq/bq so softmax uses exp2
#define QSCALE 0.1803368801111244f

typedef unsigned short u16;
typedef u16   u16x8  __attribute__((ext_vector_type(8)));
typedef __bf16 bf16x8 __attribute__((ext_vector_type(8)));
typedef __bf16 bf16x2 __attribute__((ext_vector_type(2)));
typedef float f32x4  __attribute__((ext_vector_type(4)));

typedef const __attribute__((address_space(1))) void* gas_vp;
typedef __attribute__((address_space(3))) void* las_vp;

__device__ __forceinline__ u16 f2bf(float f) {
  return __builtin_bit_cast(u16, (__bf16)f);
}

__device__ __forceinline__ uint32_t pack2bf(float a, float b) {
  bf16x2 v;
  v[0] = (__bf16)a;
  v[1] = (__bf16)b;
  return __builtin_bit_cast(uint32_t, v);
}

__device__ __forceinline__ float max3f(float a, float b, float c) {
  return fmaxf(fmaxf(a, b), c);  // clang fuses to v_max3_f32
}

__device__ __forceinline__ f32x4 mfma_bf16(u16x8 a, u16x8 b, f32x4 c) {
  return __builtin_amdgcn_mfma_f32_16x16x32_bf16(
      __builtin_bit_cast(bf16x8, a), __builtin_bit_cast(bf16x8, b), c, 0, 0, 0);
}

__device__ __forceinline__ void gload16(const u16* g, u16* l) {
  __builtin_amdgcn_global_load_lds((gas_vp)g, (las_vp)l, 16, 0, 0);
}

// ---------------- prep kernels ----------------

__global__ __launch_bounds__(256) void cast_x_kernel(const float* __restrict__ in,
                                                     u16* __restrict__ out, int n4) {
  int i = blockIdx.x * 256 + threadIdx.x;
  if (i < n4) {
    float4 v = ((const float4*)in)[i];
    ((uint2*)out)[i] = make_uint2(pack2bf(v.x, v.y), pack2bf(v.z, v.w));
  }
}

__global__ __launch_bounds__(256) void transpose_cast_kernel(
    const float* __restrict__ w0, const float* __restrict__ w1,
    const float* __restrict__ w2, const float* __restrict__ w3,
    u16* __restrict__ outQKV, u16* __restrict__ outO) {
  __shared__ float tile[32][33];
  const int m = blockIdx.z;
  const float* w = (m == 0) ? w0 : (m == 1) ? w1 : (m == 2) ? w2 : w3;
  const float scale = (m == 0) ? QSCALE : 1.0f;
  u16* out = (m < 3) ? (outQKV + (size_t)m * CDIM * CDIM) : outO;
  const int n0 = blockIdx.x * 32;
  const int k0 = blockIdx.y * 32;
  const int tx = threadIdx.x, ty = threadIdx.y;  // block (32, 8)
#pragma unroll
  for (int i = 0; i < 4; ++i)
    tile[ty + i * 8][tx] = w[(size_t)(k0 + ty + i * 8) * CDIM + n0 + tx];
  __syncthreads();
#pragma unroll
  for (int i = 0; i < 4; ++i)
    out[(size_t)(n0 + ty + i * 8) * CDIM + k0 + tx] = f2bf(tile[tx][ty + i * 8] * scale);
}

__global__ __launch_bounds__(256) void bias_concat_kernel(const float* __restrict__ bq,
                                                          const float* __restrict__ bk,
                                                          const float* __restrict__ bv,
                                                          float* __restrict__ out) {
  int i = blockIdx.x * 256 + threadIdx.x;
  if (i < 3 * CDIM) {
    float v = (i < CDIM) ? bq[i] * QSCALE
            : (i < 2 * CDIM) ? bk[i - CDIM] : bv[i - 2 * CDIM];
    out[i] = v;
  }
}

// V part of QKV [B*T][3C] -> Vt [B][H][D][T]
__global__ __launch_bounds__(256) void vtrans_kernel(const u16* __restrict__ QKV,
                                                     u16* __restrict__ Vt) {
  __shared__ u16 tile[32][33];
  const int bh = blockIdx.z;
  const int b = bh >> 4, h = bh & 15;
  const int t0 = blockIdx.x * 32, d0 = blockIdx.y * 32;
  const int tx = threadIdx.x, ty = threadIdx.y;  // block (32, 8)
#pragma unroll
  for (int i = 0; i < 4; ++i)
    tile[ty + i * 8][tx] =
        QKV[(size_t)(b * TSEQ + t0 + ty + i * 8) * (3 * CDIM) + 2 * CDIM + h * DHEAD + d0 + tx];
  __syncthreads();
#pragma unroll
  for (int i = 0; i < 4; ++i)
    Vt[(size_t)((b * NHEAD + h) * DHEAD + d0 + ty + i * 8) * TSEQ + t0 + tx] =
        tile[tx][ty + i * 8];
}

// ---------------- GEMM: C[M][N] = A[M][K] @ Bt[N][K]^T + bias ----------------
// 128x128 tile, BK=32, 4 waves, gload_lds. 2-PHASE: stage(t+1) issued BEFORE
// compute(t); one __syncthreads per K-tile. 2D XCD tiling for L2 locality.

template <typename OutT>
__global__ __launch_bounds__(256) void gemm_bt_kernel(
    const u16* __restrict__ A, const u16* __restrict__ Bt,
    const float* __restrict__ bias, OutT* __restrict__ C,
    int M, int N, int K, int nb) {
  __shared__ u16 As[2][128 * 32];
  __shared__ u16 Bs[2][128 * 32];

  const int lid = blockIdx.x;
  const int x = lid & 7;
  const int xr = x & 3, xc = x >> 2;
  const int r = lid >> 3;
  const int nloc = r >> 3;
  const int mloc = r & 7;
  const int m0 = (xr * 8 + mloc) * 128;
  const int n0 = (xc * (nb >> 1) + nloc) * 128;

  const int t = threadIdx.x;
  const int lane = t & 63;
  const int w = t >> 6;
  const int wr = w >> 1, wc = w & 1;
  const int l15 = lane & 15;
  const int lg = lane >> 4;
  const int srow = lane >> 2;
  const int scol = (lane & 3) * 8;

  f32x4 acc[4][4];
#pragma unroll
  for (int i = 0; i < 4; ++i)
#pragma unroll
    for (int j = 0; j < 4; ++j) acc[i][j] = f32x4{0.f, 0.f, 0.f, 0.f};

  const int NK = K >> 5;

#pragma unroll
  for (int ci = 0; ci < 2; ++ci) {
    const int chunk = w * 2 + ci;
    const int grow = chunk * 16 + srow;
    gload16(&A[(size_t)(m0 + grow) * K + scol], &As[0][chunk * 512]);
    gload16(&Bt[(size_t)(n0 + grow) * K + scol], &Bs[0][chunk * 512]);
  }
  __syncthreads();

  for (int it = 0; it < NK; ++it) {
    const int cur = it & 1;
    if (it + 1 < NK) {
      const int k0 = (it + 1) * 32;
#pragma unroll
      for (int ci = 0; ci < 2; ++ci) {
        const int chunk = w * 2 + ci;
        const int grow = chunk * 16 + srow;
        gload16(&A[(size_t)(m0 + grow) * K + k0 + scol], &As[cur ^ 1][chunk * 512]);
        gload16(&Bt[(size_t)(n0 + grow) * K + k0 + scol], &Bs[cur ^ 1][chunk * 512]);
      }
    }
    u16x8 af[4], bf[4];
#pragma unroll
    for (int i = 0; i < 4; ++i)
      af[i] = *(const u16x8*)(&As[cur][(wr * 64 + i * 16 + l15) * 32 + lg * 8]);
#pragma unroll
    for (int j = 0; j < 4; ++j)
      bf[j] = *(const u16x8*)(&Bs[cur][(wc * 64 + j * 16 + l15) * 32 + lg * 8]);
    __builtin_amdgcn_s_setprio(1);
#pragma unroll
    for (int i = 0; i < 4; ++i)
#pragma unroll
      for (int j = 0; j < 4; ++j) acc[i][j] = mfma_bf16(af[i], bf[j], acc[i][j]);
    __builtin_amdgcn_s_setprio(0);
    __syncthreads();
  }

#pragma unroll
  for (int j = 0; j < 4; ++j) {
    int col = n0 + wc * 64 + j * 16 + l15;
    float bv = bias[col];
#pragma unroll
    for (int i = 0; i < 4; ++i) {
#pragma unroll
      for (int r2 = 0; r2 < 4; ++r2) {
        int row = m0 + wr * 64 + i * 16 + lg * 4 + r2;
        float val = acc[i][j][r2] + bv;
        if constexpr (std::is_same<OutT, float>::value)
          C[(size_t)row * N + col] = val;
        else
          C[(size_t)row * N + col] = f2bf(val);
      }
    }
  }
}

// ---------------- causal flash attention (R12 body + zigzag balance) --------
// 4 waves x 16 q-rows (64 q/block), grid 1024, dbuf K/V, T15 S-lookahead.
// BALANCED decode: bh selector = m bits {0,6}, q-linear = m bits 1-5, qt
// zigzags heavy/light so any contiguous run of 4 blocks sums to ~62-64
// k-tiles (ideal 66) -> per-CU work is even regardless of fill order.

__global__ __launch_bounds__(256) void attn_kernel(const u16* __restrict__ QKV,
                                                   const u16* __restrict__ Vt,
                                                   u16* __restrict__ O) {
  __shared__ u16 Ks[2][64 * 64];
  __shared__ u16 Vs[2][64 * 64];
  __shared__ u16 Ps[4 * 16 * 64];

  const int t = threadIdx.x;
  const int lane = t & 63;
  const int w = t >> 6;
  const int l15 = lane & 15, lg = lane >> 4;
  const int xorv = (l15 & 7) << 4;

  // zigzag-balanced decode (bijective on lid 0..1023)
  const int lid = blockIdx.x;
  const int xcd = lid & 7;
  const int m = lid >> 3;                        // 0..127
  const int bhs = (m & 1) | ((m >> 6) << 1);     // bh selector 0..3
  const int bh = bhs * 8 + xcd;                  // 0..31
  const int ql = (m >> 1) & 31;                  // 0..31
  const int qt = (ql & 1) ? (31 - (ql >> 1)) : (ql >> 1);
  const int b = bh >> 4, h = bh & 15;
  const int q0 = qt * 64;
  const int qrow = q0 + w * 16;
  const int nkt = qt + 1;

  const size_t RS = 3 * CDIM;
  const u16* Qp  = QKV + (size_t)(b * TSEQ) * RS + h * DHEAD;
  const u16* Kp  = Qp + CDIM;
  const u16* Vgp = Vt + (size_t)(b * NHEAD + h) * DHEAD * TSEQ;
  char* PwB = (char*)&Ps[w * 16 * 64];

  u16x8 qf[2];
#pragma unroll
  for (int c = 0; c < 2; ++c)
    qf[c] = *(const u16x8*)(&Qp[(size_t)(qrow + l15) * RS + c * 32 + lg * 8]);

  f32x4 acc[4];
#pragma unroll
  for (int g = 0; g < 4; ++g) acc[g] = f32x4{0.f, 0.f, 0.f, 0.f};
  float m_run = -3e38f, l_run = 0.f;

  const int sr = t >> 2;
  const int c2 = (t & 3) * 2;
  const int swA0 = sr * 128 + ((c2 * 16) ^ ((sr & 7) << 4));
  const int swA1 = sr * 128 + (((c2 + 1) * 16) ^ ((sr & 7) << 4));

  u16x8 kreg0 = *(const u16x8*)(&Kp[(size_t)sr * RS + c2 * 8]);
  u16x8 kreg1 = *(const u16x8*)(&Kp[(size_t)sr * RS + c2 * 8 + 8]);
  u16x8 vreg0 = *(const u16x8*)(&Vgp[(size_t)sr * TSEQ + c2 * 8]);
  u16x8 vreg1 = *(const u16x8*)(&Vgp[(size_t)sr * TSEQ + c2 * 8 + 8]);
  *(u16x8*)((char*)Ks[0] + swA0) = kreg0;
  *(u16x8*)((char*)Ks[0] + swA1) = kreg1;
  *(u16x8*)((char*)Vs[0] + swA0) = vreg0;
  *(u16x8*)((char*)Vs[0] + swA1) = vreg1;
  if (nkt > 1) {
    kreg0 = *(const u16x8*)(&Kp[(size_t)(64 + sr) * RS + c2 * 8]);
    kreg1 = *(const u16x8*)(&Kp[(size_t)(64 + sr) * RS + c2 * 8 + 8]);
    vreg0 = *(const u16x8*)(&Vgp[(size_t)sr * TSEQ + 64 + c2 * 8]);
    vreg1 = *(const u16x8*)(&Vgp[(size_t)sr * TSEQ + 64 + c2 * 8 + 8]);
  }
  __syncthreads();

  f32x4 sfr[4];
#pragma unroll
  for (int f = 0; f < 4; ++f) {
    const char* rowp = (char*)Ks[0] + (f * 16 + l15) * 128;
    u16x8 k0 = *(const u16x8*)(rowp + ((lg * 16) ^ xorv));
    u16x8 k1 = *(const u16x8*)(rowp + ((64 + lg * 16) ^ xorv));
    f32x4 s = mfma_bf16(k0, qf[0], f32x4{0.f, 0.f, 0.f, 0.f});
    sfr[f] = mfma_bf16(k1, qf[1], s);
  }

  for (int kb = 0; kb < nkt; ++kb) {
    const int p = kb & 1;
    char* VsB = (char*)Vs[p];

    if (kb + 1 < nkt) {
      *(u16x8*)((char*)Ks[p ^ 1] + swA0) = kreg0;
      *(u16x8*)((char*)Ks[p ^ 1] + swA1) = kreg1;
      *(u16x8*)((char*)Vs[p ^ 1] + swA0) = vreg0;
      *(u16x8*)((char*)Vs[p ^ 1] + swA1) = vreg1;
    }
    if (kb + 2 < nkt) {
      kreg0 = *(const u16x8*)(&Kp[(size_t)((kb + 2) * 64 + sr) * RS + c2 * 8]);
      kreg1 = *(const u16x8*)(&Kp[(size_t)((kb + 2) * 64 + sr) * RS + c2 * 8 + 8]);
      vreg0 = *(const u16x8*)(&Vgp[(size_t)sr * TSEQ + (kb + 2) * 64 + c2 * 8]);
      vreg1 = *(const u16x8*)(&Vgp[(size_t)sr * TSEQ + (kb + 2) * 64 + c2 * 8 + 8]);
    }
    __syncthreads();

    f32x4 snx[4];
    if (kb + 1 < nkt) {
      __builtin_amdgcn_s_setprio(1);
#pragma unroll
      for (int f = 0; f < 4; ++f) {
        const char* rowp = (char*)Ks[p ^ 1] + (f * 16 + l15) * 128;
        u16x8 k0 = *(const u16x8*)(rowp + ((lg * 16) ^ xorv));
        u16x8 k1 = *(const u16x8*)(rowp + ((64 + lg * 16) ^ xorv));
        f32x4 s = mfma_bf16(k0, qf[0], f32x4{0.f, 0.f, 0.f, 0.f});
        snx[f] = mfma_bf16(k1, qf[1], s);
      }
      __builtin_amdgcn_s_setprio(0);
    }

    if (kb * 64 + 63 > qrow) {
      const int q_abs = qrow + l15;
#pragma unroll
      for (int f = 0; f < 4; ++f) {
        const int kbase = kb * 64 + f * 16 + lg * 4;
#pragma unroll
        for (int r = 0; r < 4; ++r)
          if (kbase + r > q_abs) sfr[f][r] = -1e9f;
      }
    }

    float t0 = max3f(sfr[0][0], sfr[0][1], sfr[0][2]);
    float t1 = max3f(sfr[0][3], sfr[1][0], sfr[1][1]);
    float t2 = max3f(sfr[1][2], sfr[1][3], sfr[2][0]);
    float t3 = max3f(sfr[2][1], sfr[2][2], sfr[2][3]);
    float t4 = max3f(sfr[3][0], sfr[3][1], sfr[3][2]);
    float mx = fmaxf(max3f(t0, t1, t2), max3f(t3, t4, sfr[3][3]));

    if (__any(mx > m_run + 8.f)) {
      float gm = mx;
      gm = fmaxf(gm, __shfl_xor(gm, 16));
      gm = fmaxf(gm, __shfl_xor(gm, 32));
      float mnew = fmaxf(m_run, gm);
      float fac = exp2f(m_run - mnew);
      m_run = mnew;
      l_run *= fac;
#pragma unroll
      for (int g = 0; g < 4; ++g) acc[g] *= fac;
    }

    {
      char* pb = PwB + l15 * 128;
      float ls = 0.f;
#pragma unroll
      for (int f = 0; f < 4; ++f) {
        float p0 = exp2f(sfr[f][0] - m_run);
        float p1 = exp2f(sfr[f][1] - m_run);
        float p2 = exp2f(sfr[f][2] - m_run);
        float p3 = exp2f(sfr[f][3] - m_run);
        ls += (p0 + p1) + (p2 + p3);
        const int boff = (f * 32 + lg * 8) ^ xorv;
        *(uint2*)(pb + boff) = make_uint2(pack2bf(p0, p1), pack2bf(p2, p3));
      }
      l_run += ls;
    }

    __builtin_amdgcn_s_setprio(1);
#pragma unroll
    for (int c = 0; c < 2; ++c) {
      const int coff = (c * 64 + lg * 16) ^ xorv;
      u16x8 pf = *(const u16x8*)(PwB + l15 * 128 + coff);
#pragma unroll
      for (int g = 0; g < 4; ++g) {
        u16x8 vf = *(const u16x8*)(VsB + (g * 16 + l15) * 128 + coff);
        acc[g] = mfma_bf16(vf, pf, acc[g]);
      }
    }
    __builtin_amdgcn_s_setprio(0);

    __syncthreads();

#pragma unroll
    for (int f = 0; f < 4; ++f) sfr[f] = snx[f];
  }

  float lt = l_run;
  lt += __shfl_xor(lt, 16);
  lt += __shfl_xor(lt, 32);
  float inv = 1.f / lt;
  {
    char* pb = PwB + l15 * 128;
#pragma unroll
    for (int g = 0; g < 4; ++g) {
      const int boff = (g * 32 + lg * 8) ^ xorv;
      *(uint2*)(pb + boff) = make_uint2(pack2bf(acc[g][0] * inv, acc[g][1] * inv),
                                        pack2bf(acc[g][2] * inv, acc[g][3] * inv));
    }
  }
#pragma unroll
  for (int i = 0; i < 2; ++i) {
    const int rl = i * 8 + (lane >> 3);
    const int ch = lane & 7;
    u16x8 vv = *(const u16x8*)(PwB + rl * 128 + ((ch * 16) ^ ((rl & 7) << 4)));
    *(u16x8*)(&O[(size_t)(b * TSEQ + qrow + rl) * CDIM + h * DHEAD + ch * 8]) = vv;
  }
}

// ---------------- launch ----------------

extern "C" void kernel_launch(void* const* d_in, const int* in_sizes, int n_in,
                              void* d_out, int out_size, void* d_ws, size_t ws_size,
                              hipStream_t stream) {
  const float* x  = (const float*)d_in[0];
  const float* wq = (const float*)d_in[1];
  const float* bq = (const float*)d_in[2];
  const float* wk = (const float*)d_in[3];
  const float* bk = (const float*)d_in[4];
  const float* wv = (const float*)d_in[5];
  const float* bv = (const float*)d_in[6];
  const float* wo = (const float*)d_in[7];
  const float* bo = (const float*)d_in[8];
  float* out = (float*)d_out;

  char* ws = (char*)d_ws;
  u16*  xb      = (u16*)(ws);                 // 8MB; dead after QKV GEMM
  u16*  Vtg     = (u16*)(ws);                 // aliases xb (written after)
  u16*  wqkvT   = (u16*)(ws + (8ll << 20));
  u16*  woT     = (u16*)(ws + (14ll << 20));
  u16*  QKV     = (u16*)(ws + (16ll << 20));
  u16*  Obuf    = (u16*)(ws + (40ll << 20));
  float* biasqkv = (float*)(ws + (48ll << 20));

  cast_x_kernel<<<(NROWS * CDIM / 4 + 255) / 256, 256, 0, stream>>>(x, xb, NROWS * CDIM / 4);
  {
    dim3 g(CDIM / 32, CDIM / 32, 4), blk(32, 8);
    transpose_cast_kernel<<<g, blk, 0, stream>>>(wq, wk, wv, wo, wqkvT, woT);
  }
  bias_concat_kernel<<<12, 256, 0, stream>>>(bq, bk, bv, biasqkv);
  gemm_bt_kernel<u16><<<(NROWS / 128) * ((3 * CDIM) / 128), 256, 0, stream>>>(
      xb, wqkvT, biasqkv, QKV, NROWS, 3 * CDIM, CDIM, (3 * CDIM) / 128);
  {
    dim3 g(TSEQ / 32, DHEAD / 32, BATCH * NHEAD), blk(32, 8);
    vtrans_kernel<<<g, blk, 0, stream>>>(QKV, Vtg);
  }
  attn_kernel<<<1024, 256, 0, stream>>>(QKV, Vtg, Obuf);
  gemm_bt_kernel<float><<<(NROWS / 128) * (CDIM / 128), 256, 0, stream>>>(
      Obuf, woT, bo, out, NROWS, CDIM, CDIM, CDIM / 128);
}

// Round 16
// 138.646 us; speedup vs baseline: 1.0485x; 1.0485x over previous
//
#include <hip/hip_runtime.h>
#include <cstdint>
#include <type_traits>

// GPT MHA forward. B=2, T=2048, C=1024, H=16, d=64.
// cast x->bf16 | transpose weights (wq pre-scaled 0.125*log2e) | bias concat
// | QKV GEMM (128x128, BK=32, gload_lds, 2-PHASE dbuf, 2D-XCD L2 tiling)
// | V-transpose | causal flash attn (R12 body + EXACT-BALANCE decode for the
//   strided block->CU mapping: per-CU work = 66 k-tiles uniform)
// | out-proj GEMM (2-phase).

#define TSEQ  2048
#define BATCH 2
#define CDIM  1024
#define NHEAD 16
#define DHEAD 64
#define NROWS (BATCH * TSEQ)  // 4096

// 0.125 (1/sqrt(d)) * log2(e): folded into wq/bq so softmax uses exp2
#define QSCALE 0.1803368801111244f

typedef unsigned short u16;
typedef u16   u16x8  __attribute__((ext_vector_type(8)));
typedef __bf16 bf16x8 __attribute__((ext_vector_type(8)));
typedef __bf16 bf16x2 __attribute__((ext_vector_type(2)));
typedef float f32x4  __attribute__((ext_vector_type(4)));

typedef const __attribute__((address_space(1))) void* gas_vp;
typedef __attribute__((address_space(3))) void* las_vp;

__device__ __forceinline__ u16 f2bf(float f) {
  return __builtin_bit_cast(u16, (__bf16)f);
}

__device__ __forceinline__ uint32_t pack2bf(float a, float b) {
  bf16x2 v;
  v[0] = (__bf16)a;
  v[1] = (__bf16)b;
  return __builtin_bit_cast(uint32_t, v);
}

__device__ __forceinline__ float max3f(float a, float b, float c) {
  return fmaxf(fmaxf(a, b), c);  // clang fuses to v_max3_f32
}

__device__ __forceinline__ f32x4 mfma_bf16(u16x8 a, u16x8 b, f32x4 c) {
  return __builtin_amdgcn_mfma_f32_16x16x32_bf16(
      __builtin_bit_cast(bf16x8, a), __builtin_bit_cast(bf16x8, b), c, 0, 0, 0);
}

__device__ __forceinline__ void gload16(const u16* g, u16* l) {
  __builtin_amdgcn_global_load_lds((gas_vp)g, (las_vp)l, 16, 0, 0);
}

// ---------------- prep kernels ----------------

__global__ __launch_bounds__(256) void cast_x_kernel(const float* __restrict__ in,
                                                     u16* __restrict__ out, int n4) {
  int i = blockIdx.x * 256 + threadIdx.x;
  if (i < n4) {
    float4 v = ((const float4*)in)[i];
    ((uint2*)out)[i] = make_uint2(pack2bf(v.x, v.y), pack2bf(v.z, v.w));
  }
}

__global__ __launch_bounds__(256) void transpose_cast_kernel(
    const float* __restrict__ w0, const float* __restrict__ w1,
    const float* __restrict__ w2, const float* __restrict__ w3,
    u16* __restrict__ outQKV, u16* __restrict__ outO) {
  __shared__ float tile[32][33];
  const int m = blockIdx.z;
  const float* w = (m == 0) ? w0 : (m == 1) ? w1 : (m == 2) ? w2 : w3;
  const float scale = (m == 0) ? QSCALE : 1.0f;
  u16* out = (m < 3) ? (outQKV + (size_t)m * CDIM * CDIM) : outO;
  const int n0 = blockIdx.x * 32;
  const int k0 = blockIdx.y * 32;
  const int tx = threadIdx.x, ty = threadIdx.y;  // block (32, 8)
#pragma unroll
  for (int i = 0; i < 4; ++i)
    tile[ty + i * 8][tx] = w[(size_t)(k0 + ty + i * 8) * CDIM + n0 + tx];
  __syncthreads();
#pragma unroll
  for (int i = 0; i < 4; ++i)
    out[(size_t)(n0 + ty + i * 8) * CDIM + k0 + tx] = f2bf(tile[tx][ty + i * 8] * scale);
}

__global__ __launch_bounds__(256) void bias_concat_kernel(const float* __restrict__ bq,
                                                          const float* __restrict__ bk,
                                                          const float* __restrict__ bv,
                                                          float* __restrict__ out) {
  int i = blockIdx.x * 256 + threadIdx.x;
  if (i < 3 * CDIM) {
    float v = (i < CDIM) ? bq[i] * QSCALE
            : (i < 2 * CDIM) ? bk[i - CDIM] : bv[i - 2 * CDIM];
    out[i] = v;
  }
}

// V part of QKV [B*T][3C] -> Vt [B][H][D][T]
__global__ __launch_bounds__(256) void vtrans_kernel(const u16* __restrict__ QKV,
                                                     u16* __restrict__ Vt) {
  __shared__ u16 tile[32][33];
  const int bh = blockIdx.z;
  const int b = bh >> 4, h = bh & 15;
  const int t0 = blockIdx.x * 32, d0 = blockIdx.y * 32;
  const int tx = threadIdx.x, ty = threadIdx.y;  // block (32, 8)
#pragma unroll
  for (int i = 0; i < 4; ++i)
    tile[ty + i * 8][tx] =
        QKV[(size_t)(b * TSEQ + t0 + ty + i * 8) * (3 * CDIM) + 2 * CDIM + h * DHEAD + d0 + tx];
  __syncthreads();
#pragma unroll
  for (int i = 0; i < 4; ++i)
    Vt[(size_t)((b * NHEAD + h) * DHEAD + d0 + ty + i * 8) * TSEQ + t0 + tx] =
        tile[tx][ty + i * 8];
}

// ---------------- GEMM: C[M][N] = A[M][K] @ Bt[N][K]^T + bias ----------------
// 128x128 tile, BK=32, 4 waves, gload_lds. 2-PHASE: stage(t+1) issued BEFORE
// compute(t); one __syncthreads per K-tile. 2D XCD tiling for L2 locality.

template <typename OutT>
__global__ __launch_bounds__(256) void gemm_bt_kernel(
    const u16* __restrict__ A, const u16* __restrict__ Bt,
    const float* __restrict__ bias, OutT* __restrict__ C,
    int M, int N, int K, int nb) {
  __shared__ u16 As[2][128 * 32];
  __shared__ u16 Bs[2][128 * 32];

  const int lid = blockIdx.x;
  const int x = lid & 7;
  const int xr = x & 3, xc = x >> 2;
  const int r = lid >> 3;
  const int nloc = r >> 3;
  const int mloc = r & 7;
  const int m0 = (xr * 8 + mloc) * 128;
  const int n0 = (xc * (nb >> 1) + nloc) * 128;

  const int t = threadIdx.x;
  const int lane = t & 63;
  const int w = t >> 6;
  const int wr = w >> 1, wc = w & 1;
  const int l15 = lane & 15;
  const int lg = lane >> 4;
  const int srow = lane >> 2;
  const int scol = (lane & 3) * 8;

  f32x4 acc[4][4];
#pragma unroll
  for (int i = 0; i < 4; ++i)
#pragma unroll
    for (int j = 0; j < 4; ++j) acc[i][j] = f32x4{0.f, 0.f, 0.f, 0.f};

  const int NK = K >> 5;

#pragma unroll
  for (int ci = 0; ci < 2; ++ci) {
    const int chunk = w * 2 + ci;
    const int grow = chunk * 16 + srow;
    gload16(&A[(size_t)(m0 + grow) * K + scol], &As[0][chunk * 512]);
    gload16(&Bt[(size_t)(n0 + grow) * K + scol], &Bs[0][chunk * 512]);
  }
  __syncthreads();

  for (int it = 0; it < NK; ++it) {
    const int cur = it & 1;
    if (it + 1 < NK) {
      const int k0 = (it + 1) * 32;
#pragma unroll
      for (int ci = 0; ci < 2; ++ci) {
        const int chunk = w * 2 + ci;
        const int grow = chunk * 16 + srow;
        gload16(&A[(size_t)(m0 + grow) * K + k0 + scol], &As[cur ^ 1][chunk * 512]);
        gload16(&Bt[(size_t)(n0 + grow) * K + k0 + scol], &Bs[cur ^ 1][chunk * 512]);
      }
    }
    u16x8 af[4], bf[4];
#pragma unroll
    for (int i = 0; i < 4; ++i)
      af[i] = *(const u16x8*)(&As[cur][(wr * 64 + i * 16 + l15) * 32 + lg * 8]);
#pragma unroll
    for (int j = 0; j < 4; ++j)
      bf[j] = *(const u16x8*)(&Bs[cur][(wc * 64 + j * 16 + l15) * 32 + lg * 8]);
    __builtin_amdgcn_s_setprio(1);
#pragma unroll
    for (int i = 0; i < 4; ++i)
#pragma unroll
      for (int j = 0; j < 4; ++j) acc[i][j] = mfma_bf16(af[i], bf[j], acc[i][j]);
    __builtin_amdgcn_s_setprio(0);
    __syncthreads();
  }

#pragma unroll
  for (int j = 0; j < 4; ++j) {
    int col = n0 + wc * 64 + j * 16 + l15;
    float bv = bias[col];
#pragma unroll
    for (int i = 0; i < 4; ++i) {
#pragma unroll
      for (int r2 = 0; r2 < 4; ++r2) {
        int row = m0 + wr * 64 + i * 16 + lg * 4 + r2;
        float val = acc[i][j][r2] + bv;
        if constexpr (std::is_same<OutT, float>::value)
          C[(size_t)row * N + col] = val;
        else
          C[(size_t)row * N + col] = f2bf(val);
      }
    }
  }
}

// ---------------- causal flash attention (R12 body + exact balance) ---------
// 4 waves x 16 q-rows (64 q/block), grid 1024 = exact residency capacity
// (4 blocks/CU). Strided mapping: CU gets blocks m, m+32, m+64, m+96.
// Decode j=m&31 (CU slot), s=m>>5 (round): qt = s odd ? 31-j : j, bhs = s
// -> per-CU work = (j+1)+(32-j)+(j+1)+(32-j) = 66 k-tiles, uniform.

__global__ __launch_bounds__(256) void attn_kernel(const u16* __restrict__ QKV,
                                                   const u16* __restrict__ Vt,
                                                   u16* __restrict__ O) {
  __shared__ u16 Ks[2][64 * 64];
  __shared__ u16 Vs[2][64 * 64];
  __shared__ u16 Ps[4 * 16 * 64];

  const int t = threadIdx.x;
  const int lane = t & 63;
  const int w = t >> 6;
  const int l15 = lane & 15, lg = lane >> 4;
  const int xorv = (l15 & 7) << 4;

  // exact-balance decode (bijective on lid 0..1023)
  const int lid = blockIdx.x;
  const int xcd = lid & 7;
  const int m = lid >> 3;           // 0..127
  const int j = m & 31;             // CU slot within XCD (strided residency)
  const int s = m >> 5;             // residency round 0..3
  const int bh = s * 8 + xcd;       // 0..31
  const int qt = (s & 1) ? (31 - j) : j;
  const int b = bh >> 4, h = bh & 15;
  const int q0 = qt * 64;
  const int qrow = q0 + w * 16;
  const int nkt = qt + 1;

  const size_t RS = 3 * CDIM;
  const u16* Qp  = QKV + (size_t)(b * TSEQ) * RS + h * DHEAD;
  const u16* Kp  = Qp + CDIM;
  const u16* Vgp = Vt + (size_t)(b * NHEAD + h) * DHEAD * TSEQ;
  char* PwB = (char*)&Ps[w * 16 * 64];

  u16x8 qf[2];
#pragma unroll
  for (int c = 0; c < 2; ++c)
    qf[c] = *(const u16x8*)(&Qp[(size_t)(qrow + l15) * RS + c * 32 + lg * 8]);

  f32x4 acc[4];
#pragma unroll
  for (int g = 0; g < 4; ++g) acc[g] = f32x4{0.f, 0.f, 0.f, 0.f};
  float m_run = -3e38f, l_run = 0.f;

  const int sr = t >> 2;
  const int c2 = (t & 3) * 2;
  const int swA0 = sr * 128 + ((c2 * 16) ^ ((sr & 7) << 4));
  const int swA1 = sr * 128 + (((c2 + 1) * 16) ^ ((sr & 7) << 4));

  u16x8 kreg0 = *(const u16x8*)(&Kp[(size_t)sr * RS + c2 * 8]);
  u16x8 kreg1 = *(const u16x8*)(&Kp[(size_t)sr * RS + c2 * 8 + 8]);
  u16x8 vreg0 = *(const u16x8*)(&Vgp[(size_t)sr * TSEQ + c2 * 8]);
  u16x8 vreg1 = *(const u16x8*)(&Vgp[(size_t)sr * TSEQ + c2 * 8 + 8]);
  *(u16x8*)((char*)Ks[0] + swA0) = kreg0;
  *(u16x8*)((char*)Ks[0] + swA1) = kreg1;
  *(u16x8*)((char*)Vs[0] + swA0) = vreg0;
  *(u16x8*)((char*)Vs[0] + swA1) = vreg1;
  if (nkt > 1) {
    kreg0 = *(const u16x8*)(&Kp[(size_t)(64 + sr) * RS + c2 * 8]);
    kreg1 = *(const u16x8*)(&Kp[(size_t)(64 + sr) * RS + c2 * 8 + 8]);
    vreg0 = *(const u16x8*)(&Vgp[(size_t)sr * TSEQ + 64 + c2 * 8]);
    vreg1 = *(const u16x8*)(&Vgp[(size_t)sr * TSEQ + 64 + c2 * 8 + 8]);
  }
  __syncthreads();

  f32x4 sfr[4];
#pragma unroll
  for (int f = 0; f < 4; ++f) {
    const char* rowp = (char*)Ks[0] + (f * 16 + l15) * 128;
    u16x8 k0 = *(const u16x8*)(rowp + ((lg * 16) ^ xorv));
    u16x8 k1 = *(const u16x8*)(rowp + ((64 + lg * 16) ^ xorv));
    f32x4 s0 = mfma_bf16(k0, qf[0], f32x4{0.f, 0.f, 0.f, 0.f});
    sfr[f] = mfma_bf16(k1, qf[1], s0);
  }

  for (int kb = 0; kb < nkt; ++kb) {
    const int p = kb & 1;
    char* VsB = (char*)Vs[p];

    if (kb + 1 < nkt) {
      *(u16x8*)((char*)Ks[p ^ 1] + swA0) = kreg0;
      *(u16x8*)((char*)Ks[p ^ 1] + swA1) = kreg1;
      *(u16x8*)((char*)Vs[p ^ 1] + swA0) = vreg0;
      *(u16x8*)((char*)Vs[p ^ 1] + swA1) = vreg1;
    }
    if (kb + 2 < nkt) {
      kreg0 = *(const u16x8*)(&Kp[(size_t)((kb + 2) * 64 + sr) * RS + c2 * 8]);
      kreg1 = *(const u16x8*)(&Kp[(size_t)((kb + 2) * 64 + sr) * RS + c2 * 8 + 8]);
      vreg0 = *(const u16x8*)(&Vgp[(size_t)sr * TSEQ + (kb + 2) * 64 + c2 * 8]);
      vreg1 = *(const u16x8*)(&Vgp[(size_t)sr * TSEQ + (kb + 2) * 64 + c2 * 8 + 8]);
    }
    __syncthreads();

    f32x4 snx[4];
    if (kb + 1 < nkt) {
      __builtin_amdgcn_s_setprio(1);
#pragma unroll
      for (int f = 0; f < 4; ++f) {
        const char* rowp = (char*)Ks[p ^ 1] + (f * 16 + l15) * 128;
        u16x8 k0 = *(const u16x8*)(rowp + ((lg * 16) ^ xorv));
        u16x8 k1 = *(const u16x8*)(rowp + ((64 + lg * 16) ^ xorv));
        f32x4 s0 = mfma_bf16(k0, qf[0], f32x4{0.f, 0.f, 0.f, 0.f});
        snx[f] = mfma_bf16(k1, qf[1], s0);
      }
      __builtin_amdgcn_s_setprio(0);
    }

    if (kb * 64 + 63 > qrow) {
      const int q_abs = qrow + l15;
#pragma unroll
      for (int f = 0; f < 4; ++f) {
        const int kbase = kb * 64 + f * 16 + lg * 4;
#pragma unroll
        for (int r = 0; r < 4; ++r)
          if (kbase + r > q_abs) sfr[f][r] = -1e9f;
      }
    }

    float t0 = max3f(sfr[0][0], sfr[0][1], sfr[0][2]);
    float t1 = max3f(sfr[0][3], sfr[1][0], sfr[1][1]);
    float t2 = max3f(sfr[1][2], sfr[1][3], sfr[2][0]);
    float t3 = max3f(sfr[2][1], sfr[2][2], sfr[2][3]);
    float t4 = max3f(sfr[3][0], sfr[3][1], sfr[3][2]);
    float mx = fmaxf(max3f(t0, t1, t2), max3f(t3, t4, sfr[3][3]));

    if (__any(mx > m_run + 8.f)) {
      float gm = mx;
      gm = fmaxf(gm, __shfl_xor(gm, 16));
      gm = fmaxf(gm, __shfl_xor(gm, 32));
      float mnew = fmaxf(m_run, gm);
      float fac = exp2f(m_run - mnew);
      m_run = mnew;
      l_run *= fac;
#pragma unroll
      for (int g = 0; g < 4; ++g) acc[g] *= fac;
    }

    {
      char* pb = PwB + l15 * 128;
      float ls = 0.f;
#pragma unroll
      for (int f = 0; f < 4; ++f) {
        float p0 = exp2f(sfr[f][0] - m_run);
        float p1 = exp2f(sfr[f][1] - m_run);
        float p2 = exp2f(sfr[f][2] - m_run);
        float p3 = exp2f(sfr[f][3] - m_run);
        ls += (p0 + p1) + (p2 + p3);
        const int boff = (f * 32 + lg * 8) ^ xorv;
        *(uint2*)(pb + boff) = make_uint2(pack2bf(p0, p1), pack2bf(p2, p3));
      }
      l_run += ls;
    }

    __builtin_amdgcn_s_setprio(1);
#pragma unroll
    for (int c = 0; c < 2; ++c) {
      const int coff = (c * 64 + lg * 16) ^ xorv;
      u16x8 pf = *(const u16x8*)(PwB + l15 * 128 + coff);
#pragma unroll
      for (int g = 0; g < 4; ++g) {
        u16x8 vf = *(const u16x8*)(VsB + (g * 16 + l15) * 128 + coff);
        acc[g] = mfma_bf16(vf, pf, acc[g]);
      }
    }
    __builtin_amdgcn_s_setprio(0);

    __syncthreads();

#pragma unroll
    for (int f = 0; f < 4; ++f) sfr[f] = snx[f];
  }

  float lt = l_run;
  lt += __shfl_xor(lt, 16);
  lt += __shfl_xor(lt, 32);
  float inv = 1.f / lt;
  {
    char* pb = PwB + l15 * 128;
#pragma unroll
    for (int g = 0; g < 4; ++g) {
      const int boff = (g * 32 + lg * 8) ^ xorv;
      *(uint2*)(pb + boff) = make_uint2(pack2bf(acc[g][0] * inv, acc[g][1] * inv),
                                        pack2bf(acc[g][2] * inv, acc[g][3] * inv));
    }
  }
#pragma unroll
  for (int i = 0; i < 2; ++i) {
    const int rl = i * 8 + (lane >> 3);
    const int ch = lane & 7;
    u16x8 vv = *(const u16x8*)(PwB + rl * 128 + ((ch * 16) ^ ((rl & 7) << 4)));
    *(u16x8*)(&O[(size_t)(b * TSEQ + qrow + rl) * CDIM + h * DHEAD + ch * 8]) = vv;
  }
}

// ---------------- launch ----------------

extern "C" void kernel_launch(void* const* d_in, const int* in_sizes, int n_in,
                              void* d_out, int out_size, void* d_ws, size_t ws_size,
                              hipStream_t stream) {
  const float* x  = (const float*)d_in[0];
  const float* wq = (const float*)d_in[1];
  const float* bq = (const float*)d_in[2];
  const float* wk = (const float*)d_in[3];
  const float* bk = (const float*)d_in[4];
  const float* wv = (const float*)d_in[5];
  const float* bv = (const float*)d_in[6];
  const float* wo = (const float*)d_in[7];
  const float* bo = (const float*)d_in[8];
  float* out = (float*)d_out;

  char* ws = (char*)d_ws;
  u16*  xb      = (u16*)(ws);                 // 8MB; dead after QKV GEMM
  u16*  Vtg     = (u16*)(ws);                 // aliases xb (written after)
  u16*  wqkvT   = (u16*)(ws + (8ll << 20));
  u16*  woT     = (u16*)(ws + (14ll << 20));
  u16*  QKV     = (u16*)(ws + (16ll << 20));
  u16*  Obuf    = (u16*)(ws + (40ll << 20));
  float* biasqkv = (float*)(ws + (48ll << 20));

  cast_x_kernel<<<(NROWS * CDIM / 4 + 255) / 256, 256, 0, stream>>>(x, xb, NROWS * CDIM / 4);
  {
    dim3 g(CDIM / 32, CDIM / 32, 4), blk(32, 8);
    transpose_cast_kernel<<<g, blk, 0, stream>>>(wq, wk, wv, wo, wqkvT, woT);
  }
  bias_concat_kernel<<<12, 256, 0, stream>>>(bq, bk, bv, biasqkv);
  gemm_bt_kernel<u16><<<(NROWS / 128) * ((3 * CDIM) / 128), 256, 0, stream>>>(
      xb, wqkvT, biasqkv, QKV, NROWS, 3 * CDIM, CDIM, (3 * CDIM) / 128);
  {
    dim3 g(TSEQ / 32, DHEAD / 32, BATCH * NHEAD), blk(32, 8);
    vtrans_kernel<<<g, blk, 0, stream>>>(QKV, Vtg);
  }
  attn_kernel<<<1024, 256, 0, stream>>>(QKV, Vtg, Obuf);
  gemm_bt_kernel<float><<<(NROWS / 128) * (CDIM / 128), 256, 0, stream>>>(
      Obuf, woT, bo, out, NROWS, CDIM, CDIM, CDIM / 128);
}

// Round 17
// 122.360 us; speedup vs baseline: 1.1881x; 1.1331x over previous
//
#include <hip/hip_runtime.h>
#include <cstdint>
#include <type_traits>

// GPT MHA forward. B=2, T=2048, C=1024, H=16, d=64.
// cast x->bf16 | transpose weights (wq pre-scaled 0.125*log2e) | bias concat
// | QKV GEMM (128x128, BK=32, gload_lds, 2-PHASE dbuf, 2D-XCD L2 tiling)
// | V-transpose | causal flash attn (R12: 4 waves x 16 q-rows, dbuf K/V,
//   T15 S-lookahead, XOR-swizzle, swapped QK^T, exp2, defer-max, R12 decode)
// | out-proj GEMM (2-phase). == R13 state (session best, 122.8 us).

#define TSEQ  2048
#define BATCH 2
#define CDIM  1024
#define NHEAD 16
#define DHEAD 64
#define NROWS (BATCH * TSEQ)  // 4096

// 0.125 (1/sqrt(d)) * log2(e): folded into wq/bq so softmax uses exp2
#define QSCALE 0.1803368801111244f

typedef unsigned short u16;
typedef u16   u16x8  __attribute__((ext_vector_type(8)));
typedef __bf16 bf16x8 __attribute__((ext_vector_type(8)));
typedef __bf16 bf16x2 __attribute__((ext_vector_type(2)));
typedef float f32x4  __attribute__((ext_vector_type(4)));

typedef const __attribute__((address_space(1))) void* gas_vp;
typedef __attribute__((address_space(3))) void* las_vp;

__device__ __forceinline__ u16 f2bf(float f) {
  return __builtin_bit_cast(u16, (__bf16)f);
}

__device__ __forceinline__ uint32_t pack2bf(float a, float b) {
  bf16x2 v;
  v[0] = (__bf16)a;
  v[1] = (__bf16)b;
  return __builtin_bit_cast(uint32_t, v);
}

__device__ __forceinline__ float max3f(float a, float b, float c) {
  return fmaxf(fmaxf(a, b), c);  // clang fuses to v_max3_f32
}

__device__ __forceinline__ f32x4 mfma_bf16(u16x8 a, u16x8 b, f32x4 c) {
  return __builtin_amdgcn_mfma_f32_16x16x32_bf16(
      __builtin_bit_cast(bf16x8, a), __builtin_bit_cast(bf16x8, b), c, 0, 0, 0);
}

__device__ __forceinline__ void gload16(const u16* g, u16* l) {
  __builtin_amdgcn_global_load_lds((gas_vp)g, (las_vp)l, 16, 0, 0);
}

// ---------------- prep kernels ----------------

__global__ __launch_bounds__(256) void cast_x_kernel(const float* __restrict__ in,
                                                     u16* __restrict__ out, int n4) {
  int i = blockIdx.x * 256 + threadIdx.x;
  if (i < n4) {
    float4 v = ((const float4*)in)[i];
    ((uint2*)out)[i] = make_uint2(pack2bf(v.x, v.y), pack2bf(v.z, v.w));
  }
}

__global__ __launch_bounds__(256) void transpose_cast_kernel(
    const float* __restrict__ w0, const float* __restrict__ w1,
    const float* __restrict__ w2, const float* __restrict__ w3,
    u16* __restrict__ outQKV, u16* __restrict__ outO) {
  __shared__ float tile[32][33];
  const int m = blockIdx.z;
  const float* w = (m == 0) ? w0 : (m == 1) ? w1 : (m == 2) ? w2 : w3;
  const float scale = (m == 0) ? QSCALE : 1.0f;
  u16* out = (m < 3) ? (outQKV + (size_t)m * CDIM * CDIM) : outO;
  const int n0 = blockIdx.x * 32;
  const int k0 = blockIdx.y * 32;
  const int tx = threadIdx.x, ty = threadIdx.y;  // block (32, 8)
#pragma unroll
  for (int i = 0; i < 4; ++i)
    tile[ty + i * 8][tx] = w[(size_t)(k0 + ty + i * 8) * CDIM + n0 + tx];
  __syncthreads();
#pragma unroll
  for (int i = 0; i < 4; ++i)
    out[(size_t)(n0 + ty + i * 8) * CDIM + k0 + tx] = f2bf(tile[tx][ty + i * 8] * scale);
}

__global__ __launch_bounds__(256) void bias_concat_kernel(const float* __restrict__ bq,
                                                          const float* __restrict__ bk,
                                                          const float* __restrict__ bv,
                                                          float* __restrict__ out) {
  int i = blockIdx.x * 256 + threadIdx.x;
  if (i < 3 * CDIM) {
    float v = (i < CDIM) ? bq[i] * QSCALE
            : (i < 2 * CDIM) ? bk[i - CDIM] : bv[i - 2 * CDIM];
    out[i] = v;
  }
}

// V part of QKV [B*T][3C] -> Vt [B][H][D][T]
__global__ __launch_bounds__(256) void vtrans_kernel(const u16* __restrict__ QKV,
                                                     u16* __restrict__ Vt) {
  __shared__ u16 tile[32][33];
  const int bh = blockIdx.z;
  const int b = bh >> 4, h = bh & 15;
  const int t0 = blockIdx.x * 32, d0 = blockIdx.y * 32;
  const int tx = threadIdx.x, ty = threadIdx.y;  // block (32, 8)
#pragma unroll
  for (int i = 0; i < 4; ++i)
    tile[ty + i * 8][tx] =
        QKV[(size_t)(b * TSEQ + t0 + ty + i * 8) * (3 * CDIM) + 2 * CDIM + h * DHEAD + d0 + tx];
  __syncthreads();
#pragma unroll
  for (int i = 0; i < 4; ++i)
    Vt[(size_t)((b * NHEAD + h) * DHEAD + d0 + ty + i * 8) * TSEQ + t0 + tx] =
        tile[tx][ty + i * 8];
}

// ---------------- GEMM: C[M][N] = A[M][K] @ Bt[N][K]^T + bias ----------------
// 128x128 tile, BK=32, 4 waves, gload_lds. 2-PHASE: stage(t+1) issued BEFORE
// compute(t); one __syncthreads per K-tile. 2D XCD tiling for L2 locality.

template <typename OutT>
__global__ __launch_bounds__(256) void gemm_bt_kernel(
    const u16* __restrict__ A, const u16* __restrict__ Bt,
    const float* __restrict__ bias, OutT* __restrict__ C,
    int M, int N, int K, int nb) {
  __shared__ u16 As[2][128 * 32];
  __shared__ u16 Bs[2][128 * 32];

  const int lid = blockIdx.x;
  const int x = lid & 7;
  const int xr = x & 3, xc = x >> 2;
  const int r = lid >> 3;
  const int nloc = r >> 3;
  const int mloc = r & 7;
  const int m0 = (xr * 8 + mloc) * 128;
  const int n0 = (xc * (nb >> 1) + nloc) * 128;

  const int t = threadIdx.x;
  const int lane = t & 63;
  const int w = t >> 6;
  const int wr = w >> 1, wc = w & 1;
  const int l15 = lane & 15;
  const int lg = lane >> 4;
  const int srow = lane >> 2;
  const int scol = (lane & 3) * 8;

  f32x4 acc[4][4];
#pragma unroll
  for (int i = 0; i < 4; ++i)
#pragma unroll
    for (int j = 0; j < 4; ++j) acc[i][j] = f32x4{0.f, 0.f, 0.f, 0.f};

  const int NK = K >> 5;

#pragma unroll
  for (int ci = 0; ci < 2; ++ci) {
    const int chunk = w * 2 + ci;
    const int grow = chunk * 16 + srow;
    gload16(&A[(size_t)(m0 + grow) * K + scol], &As[0][chunk * 512]);
    gload16(&Bt[(size_t)(n0 + grow) * K + scol], &Bs[0][chunk * 512]);
  }
  __syncthreads();

  for (int it = 0; it < NK; ++it) {
    const int cur = it & 1;
    if (it + 1 < NK) {
      const int k0 = (it + 1) * 32;
#pragma unroll
      for (int ci = 0; ci < 2; ++ci) {
        const int chunk = w * 2 + ci;
        const int grow = chunk * 16 + srow;
        gload16(&A[(size_t)(m0 + grow) * K + k0 + scol], &As[cur ^ 1][chunk * 512]);
        gload16(&Bt[(size_t)(n0 + grow) * K + k0 + scol], &Bs[cur ^ 1][chunk * 512]);
      }
    }
    u16x8 af[4], bf[4];
#pragma unroll
    for (int i = 0; i < 4; ++i)
      af[i] = *(const u16x8*)(&As[cur][(wr * 64 + i * 16 + l15) * 32 + lg * 8]);
#pragma unroll
    for (int j = 0; j < 4; ++j)
      bf[j] = *(const u16x8*)(&Bs[cur][(wc * 64 + j * 16 + l15) * 32 + lg * 8]);
    __builtin_amdgcn_s_setprio(1);
#pragma unroll
    for (int i = 0; i < 4; ++i)
#pragma unroll
      for (int j = 0; j < 4; ++j) acc[i][j] = mfma_bf16(af[i], bf[j], acc[i][j]);
    __builtin_amdgcn_s_setprio(0);
    __syncthreads();
  }

#pragma unroll
  for (int j = 0; j < 4; ++j) {
    int col = n0 + wc * 64 + j * 16 + l15;
    float bv = bias[col];
#pragma unroll
    for (int i = 0; i < 4; ++i) {
#pragma unroll
      for (int r2 = 0; r2 < 4; ++r2) {
        int row = m0 + wr * 64 + i * 16 + lg * 4 + r2;
        float val = acc[i][j][r2] + bv;
        if constexpr (std::is_same<OutT, float>::value)
          C[(size_t)row * N + col] = val;
        else
          C[(size_t)row * N + col] = f2bf(val);
      }
    }
  }
}

// ---------------- causal flash attention (R12, proven 52.5 us) --------------
// 4 waves x 16 q-rows (64 q/block), grid 1024, dbuf K/V, T15 S-lookahead:
// QK^T(kb+1) overlaps softmax(kb)+PV(kb). v_max3 tree, XOR-swizzled LDS,
// swapped QK^T, exp2 softmax, vote-gated defer-max, R12 decode (empirically
// best of 3 tested block->CU assignments; R15/R16 relabelings regressed).

__global__ __launch_bounds__(256) void attn_kernel(const u16* __restrict__ QKV,
                                                   const u16* __restrict__ Vt,
                                                   u16* __restrict__ O) {
  __shared__ u16 Ks[2][64 * 64];
  __shared__ u16 Vs[2][64 * 64];
  __shared__ u16 Ps[4 * 16 * 64];

  const int t = threadIdx.x;
  const int lane = t & 63;
  const int w = t >> 6;
  const int l15 = lane & 15, lg = lane >> 4;
  const int xorv = (l15 & 7) << 4;

  const int lid = blockIdx.x;
  const int xcd = lid & 7;
  const int m = lid >> 3;
  const int bh = (m & 3) * 8 + xcd;
  const int qt = 31 - (m >> 2);
  const int b = bh >> 4, h = bh & 15;
  const int q0 = qt * 64;
  const int qrow = q0 + w * 16;
  const int nkt = qt + 1;

  const size_t RS = 3 * CDIM;
  const u16* Qp  = QKV + (size_t)(b * TSEQ) * RS + h * DHEAD;
  const u16* Kp  = Qp + CDIM;
  const u16* Vgp = Vt + (size_t)(b * NHEAD + h) * DHEAD * TSEQ;
  char* PwB = (char*)&Ps[w * 16 * 64];

  u16x8 qf[2];
#pragma unroll
  for (int c = 0; c < 2; ++c)
    qf[c] = *(const u16x8*)(&Qp[(size_t)(qrow + l15) * RS + c * 32 + lg * 8]);

  f32x4 acc[4];
#pragma unroll
  for (int g = 0; g < 4; ++g) acc[g] = f32x4{0.f, 0.f, 0.f, 0.f};
  float m_run = -3e38f, l_run = 0.f;

  const int sr = t >> 2;
  const int c2 = (t & 3) * 2;
  const int swA0 = sr * 128 + ((c2 * 16) ^ ((sr & 7) << 4));
  const int swA1 = sr * 128 + (((c2 + 1) * 16) ^ ((sr & 7) << 4));

  u16x8 kreg0 = *(const u16x8*)(&Kp[(size_t)sr * RS + c2 * 8]);
  u16x8 kreg1 = *(const u16x8*)(&Kp[(size_t)sr * RS + c2 * 8 + 8]);
  u16x8 vreg0 = *(const u16x8*)(&Vgp[(size_t)sr * TSEQ + c2 * 8]);
  u16x8 vreg1 = *(const u16x8*)(&Vgp[(size_t)sr * TSEQ + c2 * 8 + 8]);
  *(u16x8*)((char*)Ks[0] + swA0) = kreg0;
  *(u16x8*)((char*)Ks[0] + swA1) = kreg1;
  *(u16x8*)((char*)Vs[0] + swA0) = vreg0;
  *(u16x8*)((char*)Vs[0] + swA1) = vreg1;
  if (nkt > 1) {
    kreg0 = *(const u16x8*)(&Kp[(size_t)(64 + sr) * RS + c2 * 8]);
    kreg1 = *(const u16x8*)(&Kp[(size_t)(64 + sr) * RS + c2 * 8 + 8]);
    vreg0 = *(const u16x8*)(&Vgp[(size_t)sr * TSEQ + 64 + c2 * 8]);
    vreg1 = *(const u16x8*)(&Vgp[(size_t)sr * TSEQ + 64 + c2 * 8 + 8]);
  }
  __syncthreads();

  f32x4 sfr[4];
#pragma unroll
  for (int f = 0; f < 4; ++f) {
    const char* rowp = (char*)Ks[0] + (f * 16 + l15) * 128;
    u16x8 k0 = *(const u16x8*)(rowp + ((lg * 16) ^ xorv));
    u16x8 k1 = *(const u16x8*)(rowp + ((64 + lg * 16) ^ xorv));
    f32x4 s = mfma_bf16(k0, qf[0], f32x4{0.f, 0.f, 0.f, 0.f});
    sfr[f] = mfma_bf16(k1, qf[1], s);
  }

  for (int kb = 0; kb < nkt; ++kb) {
    const int p = kb & 1;
    char* VsB = (char*)Vs[p];

    if (kb + 1 < nkt) {
      *(u16x8*)((char*)Ks[p ^ 1] + swA0) = kreg0;
      *(u16x8*)((char*)Ks[p ^ 1] + swA1) = kreg1;
      *(u16x8*)((char*)Vs[p ^ 1] + swA0) = vreg0;
      *(u16x8*)((char*)Vs[p ^ 1] + swA1) = vreg1;
    }
    if (kb + 2 < nkt) {
      kreg0 = *(const u16x8*)(&Kp[(size_t)((kb + 2) * 64 + sr) * RS + c2 * 8]);
      kreg1 = *(const u16x8*)(&Kp[(size_t)((kb + 2) * 64 + sr) * RS + c2 * 8 + 8]);
      vreg0 = *(const u16x8*)(&Vgp[(size_t)sr * TSEQ + (kb + 2) * 64 + c2 * 8]);
      vreg1 = *(const u16x8*)(&Vgp[(size_t)sr * TSEQ + (kb + 2) * 64 + c2 * 8 + 8]);
    }
    __syncthreads();

    f32x4 snx[4];
    if (kb + 1 < nkt) {
      __builtin_amdgcn_s_setprio(1);
#pragma unroll
      for (int f = 0; f < 4; ++f) {
        const char* rowp = (char*)Ks[p ^ 1] + (f * 16 + l15) * 128;
        u16x8 k0 = *(const u16x8*)(rowp + ((lg * 16) ^ xorv));
        u16x8 k1 = *(const u16x8*)(rowp + ((64 + lg * 16) ^ xorv));
        f32x4 s = mfma_bf16(k0, qf[0], f32x4{0.f, 0.f, 0.f, 0.f});
        snx[f] = mfma_bf16(k1, qf[1], s);
      }
      __builtin_amdgcn_s_setprio(0);
    }

    if (kb * 64 + 63 > qrow) {
      const int q_abs = qrow + l15;
#pragma unroll
      for (int f = 0; f < 4; ++f) {
        const int kbase = kb * 64 + f * 16 + lg * 4;
#pragma unroll
        for (int r = 0; r < 4; ++r)
          if (kbase + r > q_abs) sfr[f][r] = -1e9f;
      }
    }

    float t0 = max3f(sfr[0][0], sfr[0][1], sfr[0][2]);
    float t1 = max3f(sfr[0][3], sfr[1][0], sfr[1][1]);
    float t2 = max3f(sfr[1][2], sfr[1][3], sfr[2][0]);
    float t3 = max3f(sfr[2][1], sfr[2][2], sfr[2][3]);
    float t4 = max3f(sfr[3][0], sfr[3][1], sfr[3][2]);
    float mx = fmaxf(max3f(t0, t1, t2), max3f(t3, t4, sfr[3][3]));

    if (__any(mx > m_run + 8.f)) {
      float gm = mx;
      gm = fmaxf(gm, __shfl_xor(gm, 16));
      gm = fmaxf(gm, __shfl_xor(gm, 32));
      float mnew = fmaxf(m_run, gm);
      float fac = exp2f(m_run - mnew);
      m_run = mnew;
      l_run *= fac;
#pragma unroll
      for (int g = 0; g < 4; ++g) acc[g] *= fac;
    }

    {
      char* pb = PwB + l15 * 128;
      float ls = 0.f;
#pragma unroll
      for (int f = 0; f < 4; ++f) {
        float p0 = exp2f(sfr[f][0] - m_run);
        float p1 = exp2f(sfr[f][1] - m_run);
        float p2 = exp2f(sfr[f][2] - m_run);
        float p3 = exp2f(sfr[f][3] - m_run);
        ls += (p0 + p1) + (p2 + p3);
        const int boff = (f * 32 + lg * 8) ^ xorv;
        *(uint2*)(pb + boff) = make_uint2(pack2bf(p0, p1), pack2bf(p2, p3));
      }
      l_run += ls;
    }

    __builtin_amdgcn_s_setprio(1);
#pragma unroll
    for (int c = 0; c < 2; ++c) {
      const int coff = (c * 64 + lg * 16) ^ xorv;
      u16x8 pf = *(const u16x8*)(PwB + l15 * 128 + coff);
#pragma unroll
      for (int g = 0; g < 4; ++g) {
        u16x8 vf = *(const u16x8*)(VsB + (g * 16 + l15) * 128 + coff);
        acc[g] = mfma_bf16(vf, pf, acc[g]);
      }
    }
    __builtin_amdgcn_s_setprio(0);

    __syncthreads();

#pragma unroll
    for (int f = 0; f < 4; ++f) sfr[f] = snx[f];
  }

  float lt = l_run;
  lt += __shfl_xor(lt, 16);
  lt += __shfl_xor(lt, 32);
  float inv = 1.f / lt;
  {
    char* pb = PwB + l15 * 128;
#pragma unroll
    for (int g = 0; g < 4; ++g) {
      const int boff = (g * 32 + lg * 8) ^ xorv;
      *(uint2*)(pb + boff) = make_uint2(pack2bf(acc[g][0] * inv, acc[g][1] * inv),
                                        pack2bf(acc[g][2] * inv, acc[g][3] * inv));
    }
  }
#pragma unroll
  for (int i = 0; i < 2; ++i) {
    const int rl = i * 8 + (lane >> 3);
    const int ch = lane & 7;
    u16x8 vv = *(const u16x8*)(PwB + rl * 128 + ((ch * 16) ^ ((rl & 7) << 4)));
    *(u16x8*)(&O[(size_t)(b * TSEQ + qrow + rl) * CDIM + h * DHEAD + ch * 8]) = vv;
  }
}

// ---------------- launch ----------------

extern "C" void kernel_launch(void* const* d_in, const int* in_sizes, int n_in,
                              void* d_out, int out_size, void* d_ws, size_t ws_size,
                              hipStream_t stream) {
  const float* x  = (const float*)d_in[0];
  const float* wq = (const float*)d_in[1];
  const float* bq = (const float*)d_in[2];
  const float* wk = (const float*)d_in[3];
  const float* bk = (const float*)d_in[4];
  const float* wv = (const float*)d_in[5];
  const float* bv = (const float*)d_in[6];
  const float* wo = (const float*)d_in[7];
  const float* bo = (const float*)d_in[8];
  float* out = (float*)d_out;

  char* ws = (char*)d_ws;
  u16*  xb      = (u16*)(ws);                 // 8MB; dead after QKV GEMM
  u16*  Vtg     = (u16*)(ws);                 // aliases xb (written after)
  u16*  wqkvT   = (u16*)(ws + (8ll << 20));
  u16*  woT     = (u16*)(ws + (14ll << 20));
  u16*  QKV     = (u16*)(ws + (16ll << 20));
  u16*  Obuf    = (u16*)(ws + (40ll << 20));
  float* biasqkv = (float*)(ws + (48ll << 20));

  cast_x_kernel<<<(NROWS * CDIM / 4 + 255) / 256, 256, 0, stream>>>(x, xb, NROWS * CDIM / 4);
  {
    dim3 g(CDIM / 32, CDIM / 32, 4), blk(32, 8);
    transpose_cast_kernel<<<g, blk, 0, stream>>>(wq, wk, wv, wo, wqkvT, woT);
  }
  bias_concat_kernel<<<12, 256, 0, stream>>>(bq, bk, bv, biasqkv);
  gemm_bt_kernel<u16><<<(NROWS / 128) * ((3 * CDIM) / 128), 256, 0, stream>>>(
      xb, wqkvT, biasqkv, QKV, NROWS, 3 * CDIM, CDIM, (3 * CDIM) / 128);
  {
    dim3 g(TSEQ / 32, DHEAD / 32, BATCH * NHEAD), blk(32, 8);
    vtrans_kernel<<<g, blk, 0, stream>>>(QKV, Vtg);
  }
  attn_kernel<<<1024, 256, 0, stream>>>(QKV, Vtg, Obuf);
  gemm_bt_kernel<float><<<(NROWS / 128) * (CDIM / 128), 256, 0, stream>>>(
      Obuf, woT, bo, out, NROWS, CDIM, CDIM, CDIM / 128);
}

// Round 18
// 117.175 us; speedup vs baseline: 1.2407x; 1.0443x over previous
//
#include <hip/hip_runtime.h>
#include <cstdint>
#include <type_traits>

// GPT MHA forward. B=2, T=2048, C=1024, H=16, d=64.
// prep (ONE kernel: cast x->bf16 | transpose weights, wq pre-scaled | bias)
// | QKV GEMM (128x128, BK=32, gload_lds, 2-PHASE dbuf, 2D-XCD L2 tiling)
// | V-transpose | causal flash attn (R12: 4 waves x 16 q-rows, dbuf K/V,
//   T15 S-lookahead, XOR-swizzle, swapped QK^T, exp2, defer-max)
// | out-proj GEMM (2-phase).

#define TSEQ  2048
#define BATCH 2
#define CDIM  1024
#define NHEAD 16
#define DHEAD 64
#define NROWS (BATCH * TSEQ)  // 4096

// 0.125 (1/sqrt(d)) * log2(e): folded into wq/bq so softmax uses exp2
#define QSCALE 0.1803368801111244f

typedef unsigned short u16;
typedef u16   u16x8  __attribute__((ext_vector_type(8)));
typedef __bf16 bf16x8 __attribute__((ext_vector_type(8)));
typedef __bf16 bf16x2 __attribute__((ext_vector_type(2)));
typedef float f32x4  __attribute__((ext_vector_type(4)));

typedef const __attribute__((address_space(1))) void* gas_vp;
typedef __attribute__((address_space(3))) void* las_vp;

__device__ __forceinline__ u16 f2bf(float f) {
  return __builtin_bit_cast(u16, (__bf16)f);
}

__device__ __forceinline__ uint32_t pack2bf(float a, float b) {
  bf16x2 v;
  v[0] = (__bf16)a;
  v[1] = (__bf16)b;
  return __builtin_bit_cast(uint32_t, v);
}

__device__ __forceinline__ float max3f(float a, float b, float c) {
  return fmaxf(fmaxf(a, b), c);  // clang fuses to v_max3_f32
}

__device__ __forceinline__ f32x4 mfma_bf16(u16x8 a, u16x8 b, f32x4 c) {
  return __builtin_amdgcn_mfma_f32_16x16x32_bf16(
      __builtin_bit_cast(bf16x8, a), __builtin_bit_cast(bf16x8, b), c, 0, 0, 0);
}

__device__ __forceinline__ void gload16(const u16* g, u16* l) {
  __builtin_amdgcn_global_load_lds((gas_vp)g, (las_vp)l, 16, 0, 0);
}

// ---------------- unified prep kernel (cast + transpose + bias) ----------------
// blocks [0,4096): cast x fp32->bf16 (float4/thread)
// blocks [4096,8192): 32x32 transpose+cast of wq/wk/wv/wo (wq scaled QSCALE)
// blocks [8192,8204): bias concat (bq scaled QSCALE)

__global__ __launch_bounds__(256) void prep_kernel(
    const float* __restrict__ x,
    const float* __restrict__ w0, const float* __restrict__ w1,
    const float* __restrict__ w2, const float* __restrict__ w3,
    const float* __restrict__ bq, const float* __restrict__ bk,
    const float* __restrict__ bv,
    u16* __restrict__ xb, u16* __restrict__ outQKV, u16* __restrict__ outO,
    float* __restrict__ biasqkv) {
  __shared__ float tile[32][33];
  const int blk = blockIdx.x;
  const int tid = threadIdx.x;

  if (blk < 4096) {  // cast x
    int i = blk * 256 + tid;  // < 1048576 = NROWS*CDIM/4
    float4 v = ((const float4*)x)[i];
    ((uint2*)xb)[i] = make_uint2(pack2bf(v.x, v.y), pack2bf(v.z, v.w));
  } else if (blk < 8192) {  // weight transpose+cast
    const int idx = blk - 4096;
    const int m = idx >> 10;          // 0..3
    const int rem = idx & 1023;
    const int n0 = (rem & 31) * 32;
    const int k0 = (rem >> 5) * 32;
    const float* w = (m == 0) ? w0 : (m == 1) ? w1 : (m == 2) ? w2 : w3;
    const float scale = (m == 0) ? QSCALE : 1.0f;
    u16* out = (m < 3) ? (outQKV + (size_t)m * CDIM * CDIM) : outO;
    const int tx = tid & 31, ty = tid >> 5;  // (32, 8)
#pragma unroll
    for (int i = 0; i < 4; ++i)
      tile[ty + i * 8][tx] = w[(size_t)(k0 + ty + i * 8) * CDIM + n0 + tx];
    __syncthreads();
#pragma unroll
    for (int i = 0; i < 4; ++i)
      out[(size_t)(n0 + ty + i * 8) * CDIM + k0 + tx] = f2bf(tile[tx][ty + i * 8] * scale);
  } else {  // bias concat
    int i = (blk - 8192) * 256 + tid;
    if (i < 3 * CDIM) {
      float v = (i < CDIM) ? bq[i] * QSCALE
              : (i < 2 * CDIM) ? bk[i - CDIM] : bv[i - 2 * CDIM];
      biasqkv[i] = v;
    }
  }
}

// V part of QKV [B*T][3C] -> Vt [B][H][D][T]
__global__ __launch_bounds__(256) void vtrans_kernel(const u16* __restrict__ QKV,
                                                     u16* __restrict__ Vt) {
  __shared__ u16 tile[32][33];
  const int bh = blockIdx.z;
  const int b = bh >> 4, h = bh & 15;
  const int t0 = blockIdx.x * 32, d0 = blockIdx.y * 32;
  const int tx = threadIdx.x, ty = threadIdx.y;  // block (32, 8)
#pragma unroll
  for (int i = 0; i < 4; ++i)
    tile[ty + i * 8][tx] =
        QKV[(size_t)(b * TSEQ + t0 + ty + i * 8) * (3 * CDIM) + 2 * CDIM + h * DHEAD + d0 + tx];
  __syncthreads();
#pragma unroll
  for (int i = 0; i < 4; ++i)
    Vt[(size_t)((b * NHEAD + h) * DHEAD + d0 + ty + i * 8) * TSEQ + t0 + tx] =
        tile[tx][ty + i * 8];
}

// ---------------- GEMM: C[M][N] = A[M][K] @ Bt[N][K]^T + bias ----------------
// 128x128 tile, BK=32, 4 waves, gload_lds. 2-PHASE: stage(t+1) issued BEFORE
// compute(t); one __syncthreads per K-tile. 2D XCD tiling for L2 locality.

template <typename OutT>
__global__ __launch_bounds__(256) void gemm_bt_kernel(
    const u16* __restrict__ A, const u16* __restrict__ Bt,
    const float* __restrict__ bias, OutT* __restrict__ C,
    int M, int N, int K, int nb) {
  __shared__ u16 As[2][128 * 32];
  __shared__ u16 Bs[2][128 * 32];

  const int lid = blockIdx.x;
  const int x = lid & 7;
  const int xr = x & 3, xc = x >> 2;
  const int r = lid >> 3;
  const int nloc = r >> 3;
  const int mloc = r & 7;
  const int m0 = (xr * 8 + mloc) * 128;
  const int n0 = (xc * (nb >> 1) + nloc) * 128;

  const int t = threadIdx.x;
  const int lane = t & 63;
  const int w = t >> 6;
  const int wr = w >> 1, wc = w & 1;
  const int l15 = lane & 15;
  const int lg = lane >> 4;
  const int srow = lane >> 2;
  const int scol = (lane & 3) * 8;

  f32x4 acc[4][4];
#pragma unroll
  for (int i = 0; i < 4; ++i)
#pragma unroll
    for (int j = 0; j < 4; ++j) acc[i][j] = f32x4{0.f, 0.f, 0.f, 0.f};

  const int NK = K >> 5;

#pragma unroll
  for (int ci = 0; ci < 2; ++ci) {
    const int chunk = w * 2 + ci;
    const int grow = chunk * 16 + srow;
    gload16(&A[(size_t)(m0 + grow) * K + scol], &As[0][chunk * 512]);
    gload16(&Bt[(size_t)(n0 + grow) * K + scol], &Bs[0][chunk * 512]);
  }
  __syncthreads();

  for (int it = 0; it < NK; ++it) {
    const int cur = it & 1;
    if (it + 1 < NK) {
      const int k0 = (it + 1) * 32;
#pragma unroll
      for (int ci = 0; ci < 2; ++ci) {
        const int chunk = w * 2 + ci;
        const int grow = chunk * 16 + srow;
        gload16(&A[(size_t)(m0 + grow) * K + k0 + scol], &As[cur ^ 1][chunk * 512]);
        gload16(&Bt[(size_t)(n0 + grow) * K + k0 + scol], &Bs[cur ^ 1][chunk * 512]);
      }
    }
    u16x8 af[4], bf[4];
#pragma unroll
    for (int i = 0; i < 4; ++i)
      af[i] = *(const u16x8*)(&As[cur][(wr * 64 + i * 16 + l15) * 32 + lg * 8]);
#pragma unroll
    for (int j = 0; j < 4; ++j)
      bf[j] = *(const u16x8*)(&Bs[cur][(wc * 64 + j * 16 + l15) * 32 + lg * 8]);
    __builtin_amdgcn_s_setprio(1);
#pragma unroll
    for (int i = 0; i < 4; ++i)
#pragma unroll
      for (int j = 0; j < 4; ++j) acc[i][j] = mfma_bf16(af[i], bf[j], acc[i][j]);
    __builtin_amdgcn_s_setprio(0);
    __syncthreads();
  }

#pragma unroll
  for (int j = 0; j < 4; ++j) {
    int col = n0 + wc * 64 + j * 16 + l15;
    float bv = bias[col];
#pragma unroll
    for (int i = 0; i < 4; ++i) {
#pragma unroll
      for (int r2 = 0; r2 < 4; ++r2) {
        int row = m0 + wr * 64 + i * 16 + lg * 4 + r2;
        float val = acc[i][j][r2] + bv;
        if constexpr (std::is_same<OutT, float>::value)
          C[(size_t)row * N + col] = val;
        else
          C[(size_t)row * N + col] = f2bf(val);
      }
    }
  }
}

// ---------------- causal flash attention (R12, proven 52.5 us) --------------

__global__ __launch_bounds__(256) void attn_kernel(const u16* __restrict__ QKV,
                                                   const u16* __restrict__ Vt,
                                                   u16* __restrict__ O) {
  __shared__ u16 Ks[2][64 * 64];
  __shared__ u16 Vs[2][64 * 64];
  __shared__ u16 Ps[4 * 16 * 64];

  const int t = threadIdx.x;
  const int lane = t & 63;
  const int w = t >> 6;
  const int l15 = lane & 15, lg = lane >> 4;
  const int xorv = (l15 & 7) << 4;

  const int lid = blockIdx.x;
  const int xcd = lid & 7;
  const int m = lid >> 3;
  const int bh = (m & 3) * 8 + xcd;
  const int qt = 31 - (m >> 2);
  const int b = bh >> 4, h = bh & 15;
  const int q0 = qt * 64;
  const int qrow = q0 + w * 16;
  const int nkt = qt + 1;

  const size_t RS = 3 * CDIM;
  const u16* Qp  = QKV + (size_t)(b * TSEQ) * RS + h * DHEAD;
  const u16* Kp  = Qp + CDIM;
  const u16* Vgp = Vt + (size_t)(b * NHEAD + h) * DHEAD * TSEQ;
  char* PwB = (char*)&Ps[w * 16 * 64];

  u16x8 qf[2];
#pragma unroll
  for (int c = 0; c < 2; ++c)
    qf[c] = *(const u16x8*)(&Qp[(size_t)(qrow + l15) * RS + c * 32 + lg * 8]);

  f32x4 acc[4];
#pragma unroll
  for (int g = 0; g < 4; ++g) acc[g] = f32x4{0.f, 0.f, 0.f, 0.f};
  float m_run = -3e38f, l_run = 0.f;

  const int sr = t >> 2;
  const int c2 = (t & 3) * 2;
  const int swA0 = sr * 128 + ((c2 * 16) ^ ((sr & 7) << 4));
  const int swA1 = sr * 128 + (((c2 + 1) * 16) ^ ((sr & 7) << 4));

  u16x8 kreg0 = *(const u16x8*)(&Kp[(size_t)sr * RS + c2 * 8]);
  u16x8 kreg1 = *(const u16x8*)(&Kp[(size_t)sr * RS + c2 * 8 + 8]);
  u16x8 vreg0 = *(const u16x8*)(&Vgp[(size_t)sr * TSEQ + c2 * 8]);
  u16x8 vreg1 = *(const u16x8*)(&Vgp[(size_t)sr * TSEQ + c2 * 8 + 8]);
  *(u16x8*)((char*)Ks[0] + swA0) = kreg0;
  *(u16x8*)((char*)Ks[0] + swA1) = kreg1;
  *(u16x8*)((char*)Vs[0] + swA0) = vreg0;
  *(u16x8*)((char*)Vs[0] + swA1) = vreg1;
  if (nkt > 1) {
    kreg0 = *(const u16x8*)(&Kp[(size_t)(64 + sr) * RS + c2 * 8]);
    kreg1 = *(const u16x8*)(&Kp[(size_t)(64 + sr) * RS + c2 * 8 + 8]);
    vreg0 = *(const u16x8*)(&Vgp[(size_t)sr * TSEQ + 64 + c2 * 8]);
    vreg1 = *(const u16x8*)(&Vgp[(size_t)sr * TSEQ + 64 + c2 * 8 + 8]);
  }
  __syncthreads();

  f32x4 sfr[4];
#pragma unroll
  for (int f = 0; f < 4; ++f) {
    const char* rowp = (char*)Ks[0] + (f * 16 + l15) * 128;
    u16x8 k0 = *(const u16x8*)(rowp + ((lg * 16) ^ xorv));
    u16x8 k1 = *(const u16x8*)(rowp + ((64 + lg * 16) ^ xorv));
    f32x4 s = mfma_bf16(k0, qf[0], f32x4{0.f, 0.f, 0.f, 0.f});
    sfr[f] = mfma_bf16(k1, qf[1], s);
  }

  for (int kb = 0; kb < nkt; ++kb) {
    const int p = kb & 1;
    char* VsB = (char*)Vs[p];

    if (kb + 1 < nkt) {
      *(u16x8*)((char*)Ks[p ^ 1] + swA0) = kreg0;
      *(u16x8*)((char*)Ks[p ^ 1] + swA1) = kreg1;
      *(u16x8*)((char*)Vs[p ^ 1] + swA0) = vreg0;
      *(u16x8*)((char*)Vs[p ^ 1] + swA1) = vreg1;
    }
    if (kb + 2 < nkt) {
      kreg0 = *(const u16x8*)(&Kp[(size_t)((kb + 2) * 64 + sr) * RS + c2 * 8]);
      kreg1 = *(const u16x8*)(&Kp[(size_t)((kb + 2) * 64 + sr) * RS + c2 * 8 + 8]);
      vreg0 = *(const u16x8*)(&Vgp[(size_t)sr * TSEQ + (kb + 2) * 64 + c2 * 8]);
      vreg1 = *(const u16x8*)(&Vgp[(size_t)sr * TSEQ + (kb + 2) * 64 + c2 * 8 + 8]);
    }
    __syncthreads();

    f32x4 snx[4];
    if (kb + 1 < nkt) {
      __builtin_amdgcn_s_setprio(1);
#pragma unroll
      for (int f = 0; f < 4; ++f) {
        const char* rowp = (char*)Ks[p ^ 1] + (f * 16 + l15) * 128;
        u16x8 k0 = *(const u16x8*)(rowp + ((lg * 16) ^ xorv));
        u16x8 k1 = *(const u16x8*)(rowp + ((64 + lg * 16) ^ xorv));
        f32x4 s = mfma_bf16(k0, qf[0], f32x4{0.f, 0.f, 0.f, 0.f});
        snx[f] = mfma_bf16(k1, qf[1], s);
      }
      __builtin_amdgcn_s_setprio(0);
    }

    if (kb * 64 + 63 > qrow) {
      const int q_abs = qrow + l15;
#pragma unroll
      for (int f = 0; f < 4; ++f) {
        const int kbase = kb * 64 + f * 16 + lg * 4;
#pragma unroll
        for (int r = 0; r < 4; ++r)
          if (kbase + r > q_abs) sfr[f][r] = -1e9f;
      }
    }

    float t0 = max3f(sfr[0][0], sfr[0][1], sfr[0][2]);
    float t1 = max3f(sfr[0][3], sfr[1][0], sfr[1][1]);
    float t2 = max3f(sfr[1][2], sfr[1][3], sfr[2][0]);
    float t3 = max3f(sfr[2][1], sfr[2][2], sfr[2][3]);
    float t4 = max3f(sfr[3][0], sfr[3][1], sfr[3][2]);
    float mx = fmaxf(max3f(t0, t1, t2), max3f(t3, t4, sfr[3][3]));

    if (__any(mx > m_run + 8.f)) {
      float gm = mx;
      gm = fmaxf(gm, __shfl_xor(gm, 16));
      gm = fmaxf(gm, __shfl_xor(gm, 32));
      float mnew = fmaxf(m_run, gm);
      float fac = exp2f(m_run - mnew);
      m_run = mnew;
      l_run *= fac;
#pragma unroll
      for (int g = 0; g < 4; ++g) acc[g] *= fac;
    }

    {
      char* pb = PwB + l15 * 128;
      float ls = 0.f;
#pragma unroll
      for (int f = 0; f < 4; ++f) {
        float p0 = exp2f(sfr[f][0] - m_run);
        float p1 = exp2f(sfr[f][1] - m_run);
        float p2 = exp2f(sfr[f][2] - m_run);
        float p3 = exp2f(sfr[f][3] - m_run);
        ls += (p0 + p1) + (p2 + p3);
        const int boff = (f * 32 + lg * 8) ^ xorv;
        *(uint2*)(pb + boff) = make_uint2(pack2bf(p0, p1), pack2bf(p2, p3));
      }
      l_run += ls;
    }

    __builtin_amdgcn_s_setprio(1);
#pragma unroll
    for (int c = 0; c < 2; ++c) {
      const int coff = (c * 64 + lg * 16) ^ xorv;
      u16x8 pf = *(const u16x8*)(PwB + l15 * 128 + coff);
#pragma unroll
      for (int g = 0; g < 4; ++g) {
        u16x8 vf = *(const u16x8*)(VsB + (g * 16 + l15) * 128 + coff);
        acc[g] = mfma_bf16(vf, pf, acc[g]);
      }
    }
    __builtin_amdgcn_s_setprio(0);

    __syncthreads();

#pragma unroll
    for (int f = 0; f < 4; ++f) sfr[f] = snx[f];
  }

  float lt = l_run;
  lt += __shfl_xor(lt, 16);
  lt += __shfl_xor(lt, 32);
  float inv = 1.f / lt;
  {
    char* pb = PwB + l15 * 128;
#pragma unroll
    for (int g = 0; g < 4; ++g) {
      const int boff = (g * 32 + lg * 8) ^ xorv;
      *(uint2*)(pb + boff) = make_uint2(pack2bf(acc[g][0] * inv, acc[g][1] * inv),
                                        pack2bf(acc[g][2] * inv, acc[g][3] * inv));
    }
  }
#pragma unroll
  for (int i = 0; i < 2; ++i) {
    const int rl = i * 8 + (lane >> 3);
    const int ch = lane & 7;
    u16x8 vv = *(const u16x8*)(PwB + rl * 128 + ((ch * 16) ^ ((rl & 7) << 4)));
    *(u16x8*)(&O[(size_t)(b * TSEQ + qrow + rl) * CDIM + h * DHEAD + ch * 8]) = vv;
  }
}

// ---------------- launch ----------------

extern "C" void kernel_launch(void* const* d_in, const int* in_sizes, int n_in,
                              void* d_out, int out_size, void* d_ws, size_t ws_size,
                              hipStream_t stream) {
  const float* x  = (const float*)d_in[0];
  const float* wq = (const float*)d_in[1];
  const float* bq = (const float*)d_in[2];
  const float* wk = (const float*)d_in[3];
  const float* bk = (const float*)d_in[4];
  const float* wv = (const float*)d_in[5];
  const float* bv = (const float*)d_in[6];
  const float* wo = (const float*)d_in[7];
  const float* bo = (const float*)d_in[8];
  float* out = (float*)d_out;

  char* ws = (char*)d_ws;
  u16*  xb      = (u16*)(ws);                 // 8MB; dead after QKV GEMM
  u16*  Vtg     = (u16*)(ws);                 // aliases xb (written after)
  u16*  wqkvT   = (u16*)(ws + (8ll << 20));
  u16*  woT     = (u16*)(ws + (14ll << 20));
  u16*  QKV     = (u16*)(ws + (16ll << 20));
  u16*  Obuf    = (u16*)(ws + (40ll << 20));
  float* biasqkv = (float*)(ws + (48ll << 20));

  prep_kernel<<<8204, 256, 0, stream>>>(x, wq, wk, wv, wo, bq, bk, bv,
                                        xb, wqkvT, woT, biasqkv);
  gemm_bt_kernel<u16><<<(NROWS / 128) * ((3 * CDIM) / 128), 256, 0, stream>>>(
      xb, wqkvT, biasqkv, QKV, NROWS, 3 * CDIM, CDIM, (3 * CDIM) / 128);
  {
    dim3 g(TSEQ / 32, DHEAD / 32, BATCH * NHEAD), blk(32, 8);
    vtrans_kernel<<<g, blk, 0, stream>>>(QKV, Vtg);
  }
  attn_kernel<<<1024, 256, 0, stream>>>(QKV, Vtg, Obuf);
  gemm_bt_kernel<float><<<(NROWS / 128) * (CDIM / 128), 256, 0, stream>>>(
      Obuf, woT, bo, out, NROWS, CDIM, CDIM, CDIM / 128);
}